// Round 6
// baseline (846.763 us; speedup 1.0000x reference)
//
#include <hip/hip_runtime.h>
#include <hip/hip_bf16.h>

#define M_TOK 2048
#define K_DIM 1024
#define E_NUM 8
#define DFF   2816
#define TOPK  2
#define NROWS (M_TOK*TOPK)   // 4096 routed rows

typedef __bf16 bf16;
typedef __bf16 bf16x8 __attribute__((ext_vector_type(8)));
typedef float  f32x4  __attribute__((ext_vector_type(4)));

// ---------------------------------------------------------------------------
// Routing (unchanged, verified): per-expert compacted token lists.
// ---------------------------------------------------------------------------
__global__ __launch_bounds__(512)
void route_kernel(const int* __restrict__ ids,
                  const float* __restrict__ tw,
                  int* __restrict__ counts, int* __restrict__ offs,
                  int* __restrict__ row_token, float* __restrict__ row_wgt)
{
    const int e    = threadIdx.x >> 6;
    const int lane = threadIdx.x & 63;
    __shared__ int scnt[E_NUM];

    int cnt = 0;
    for (int i0 = 0; i0 < NROWS; i0 += 64) {
        int id = ids[i0 + lane];
        cnt += __popcll(__ballot(id == e));
    }
    if (lane == 0) scnt[e] = cnt;
    __syncthreads();
    int base = 0;
    for (int j = 0; j < e; ++j) base += scnt[j];
    if (lane == 0) { counts[e] = cnt; offs[e] = base; }

    const unsigned long long ltmask = (1ull << lane) - 1ull;
    int pos = base;
    for (int i0 = 0; i0 < NROWS; i0 += 64) {
        int i = i0 + lane;
        int id = ids[i];
        unsigned long long m = __ballot(id == e);
        if (id == e) {
            int rank = __popcll(m & ltmask);
            row_token[pos + rank] = i >> 1;      // TOPK==2
            row_wgt[pos + rank]   = tw[i];
        }
        pos += __popcll(m);
    }
}

// ---------------------------------------------------------------------------
// GEMM1 + silu_and_mul. Tile 128 rows x 64 act-cols (B = 64 gate + 64 up rows).
// SINGLE-buffered LDS (32 KiB -> 5 blocks/CU) + 1-deep reg prefetch:
//   loop: [bar] STORE(kt) / LOAD(kt+1) [bar] COMPUTE(kt)
// TLP (20 waves/CU) hides the ~900cy load latency that ILP couldn't.
// ---------------------------------------------------------------------------
__global__ __launch_bounds__(256, 4)
void gemm1_kernel(const float* __restrict__ X, const float* __restrict__ w1,
                  const int* __restrict__ counts, const int* __restrict__ offs,
                  const int* __restrict__ row_token, bf16* __restrict__ act)
{
    const int e  = blockIdx.z;
    const int rt = blockIdx.y;
    const int ct = blockIdx.x;              // 0..43
    const int n  = counts[e];
    const int r0 = rt * 128;
    if (r0 >= n) return;
    const int base = offs[e];

    __shared__ __align__(16) bf16 As[128*64];
    __shared__ __align__(16) bf16 Bs[128*64];
    bf16x8* Asv = (bf16x8*)As;
    bf16x8* Bsv = (bf16x8*)Bs;

    const int t   = threadIdx.x;
    const int rq0 = t >> 3;                 // 0..31
    const int ju  = t & 7;                  // 32B unit within 256B row-slice

    const float* aRow[4];
    const float* bRow[4];
    #pragma unroll
    for (int q = 0; q < 4; ++q) {
        int rl = r0 + q*32 + rq0; if (rl > n - 1) rl = n - 1;
        aRow[q] = X + (size_t)row_token[base + rl] * K_DIM + ju*8;
        int brow = q*32 + rq0;              // 0..127
        int w1row = (brow < 64) ? (ct*64 + brow) : (DFF + ct*64 + brow - 64);
        bRow[q] = w1 + ((size_t)e * (2*DFF) + w1row) * K_DIM + ju*8;
    }

    const int lane = t & 63, wv = t >> 6;
    const int wr = wv >> 1, wc = wv & 1;
    const int l15 = lane & 15, lq = lane >> 4;

    f32x4 accG[4][2], accU[4][2];
    #pragma unroll
    for (int m = 0; m < 4; ++m)
        #pragma unroll
        for (int nn = 0; nn < 2; ++nn) {
            accG[m][nn] = (f32x4){0.f,0.f,0.f,0.f};
            accU[m][nn] = (f32x4){0.f,0.f,0.f,0.f};
        }

    f32x4 ra[8], rb[8];

#define G1_LOAD(KT_) do { \
    _Pragma("unroll") for (int q = 0; q < 4; ++q) { \
        const f32x4* ap_ = (const f32x4*)(aRow[q] + (KT_)*64); \
        ra[2*q] = ap_[0]; ra[2*q+1] = ap_[1]; \
        const f32x4* bp_ = (const f32x4*)(bRow[q] + (KT_)*64); \
        rb[2*q] = bp_[0]; rb[2*q+1] = bp_[1]; \
    } } while (0)

#define G1_STORE() do { \
    _Pragma("unroll") for (int q = 0; q < 4; ++q) { \
        int rq_ = q*32 + rq0; \
        f32x4 lo = ra[2*q], hi = ra[2*q+1]; bf16x8 v; \
        _Pragma("unroll") for (int j = 0; j < 4; ++j) { v[j]=(bf16)lo[j]; v[j+4]=(bf16)hi[j]; } \
        Asv[rq_*8 + (ju ^ (rq_ & 7))] = v; \
        f32x4 lo2 = rb[2*q], hi2 = rb[2*q+1]; bf16x8 v2; \
        _Pragma("unroll") for (int j = 0; j < 4; ++j) { v2[j]=(bf16)lo2[j]; v2[j+4]=(bf16)hi2[j]; } \
        Bsv[rq_*8 + (ju ^ (rq_ & 7))] = v2; \
    } } while (0)

#define G1_COMPUTE() do { \
    _Pragma("unroll") for (int ks = 0; ks < 2; ++ks) { \
        bf16x8 af[4], bg[2], bu[2]; \
        _Pragma("unroll") for (int m = 0; m < 4; ++m) { \
            int fr = wr*64 + m*16 + l15; \
            af[m] = Asv[fr*8 + ((ks*4 + lq) ^ (fr & 7))]; \
        } \
        _Pragma("unroll") for (int nn = 0; nn < 2; ++nn) { \
            int frg = wc*32 + nn*16 + l15; \
            bg[nn] = Bsv[frg*8 + ((ks*4 + lq) ^ (frg & 7))]; \
            int fru = 64 + wc*32 + nn*16 + l15; \
            bu[nn] = Bsv[fru*8 + ((ks*4 + lq) ^ (fru & 7))]; \
        } \
        _Pragma("unroll") for (int m = 0; m < 4; ++m) \
            _Pragma("unroll") for (int nn = 0; nn < 2; ++nn) { \
                accG[m][nn] = __builtin_amdgcn_mfma_f32_16x16x32_bf16(af[m], bg[nn], accG[m][nn], 0, 0, 0); \
                accU[m][nn] = __builtin_amdgcn_mfma_f32_16x16x32_bf16(af[m], bu[nn], accU[m][nn], 0, 0, 0); \
            } \
    } } while (0)

    const int KT = K_DIM / 64;   // 16
    G1_LOAD(0);
    for (int kt = 0; kt < KT; ++kt) {
        if (kt) __syncthreads();            // prev compute done reading buf
        G1_STORE();                          // waits on LOAD(kt)
        if (kt + 1 < KT) G1_LOAD(kt + 1);   // in flight across compute
        __syncthreads();
        G1_COMPUTE();
    }

    // epilogue: act = silu(gate) * up  (C/D: col=lane&15, row=(lane>>4)*4+r)
    #pragma unroll
    for (int m = 0; m < 4; ++m)
        #pragma unroll
        for (int nn = 0; nn < 2; ++nn)
            #pragma unroll
            for (int r = 0; r < 4; ++r) {
                int rl = wr*64 + m*16 + lq*4 + r;
                int grow = r0 + rl;
                if (grow < n) {
                    float g = accG[m][nn][r];
                    float u = accU[m][nn][r];
                    float a = (g / (1.f + __expf(-g))) * u;
                    int col = ct*64 + wc*32 + nn*16 + l15;
                    act[(size_t)(base + grow) * DFF + col] = (bf16)a;
                }
            }
#undef G1_LOAD
#undef G1_STORE
#undef G1_COMPUTE
}

// ---------------------------------------------------------------------------
// GEMM2: y = act @ w2[e]^T, atomic scatter epilogue. Tile 128 x 128.
// SINGLE-buffered LDS + KSPLIT=2 + 1-deep reg prefetch (same schedule).
// ---------------------------------------------------------------------------
#define KSPLIT 2
#define KT2    (DFF / 64 / KSPLIT)   // 22

__global__ __launch_bounds__(256, 4)
void gemm2_kernel(const bf16* __restrict__ act, const float* __restrict__ w2,
                  const int* __restrict__ counts, const int* __restrict__ offs,
                  const int* __restrict__ row_token, const float* __restrict__ row_wgt,
                  float* __restrict__ out)
{
    const int e   = blockIdx.z;
    const int rt  = blockIdx.y;
    const int ct  = blockIdx.x >> 1;          // 0..7 : 128 out cols
    const int ksp = blockIdx.x & 1;           // DFF half
    const int n   = counts[e];
    const int r0  = rt * 128;
    if (r0 >= n) return;
    const int base = offs[e];

    __shared__ __align__(16) bf16 As[128*64];
    __shared__ __align__(16) bf16 Bs[128*64];
    bf16x8* Asv = (bf16x8*)As;
    bf16x8* Bsv = (bf16x8*)Bs;

    const int t = threadIdx.x;
    const int rqa = t >> 2, jua = t & 3;      // A: 4 units(32B) per 128B row
    const int rqb = t >> 3, jub = t & 7;      // B: 8 units(32B) per 256B row

    const bf16* aRow[2];
    #pragma unroll
    for (int q = 0; q < 2; ++q) {
        int rl = r0 + q*64 + rqa; if (rl > n - 1) rl = n - 1;
        aRow[q] = act + (size_t)(base + rl) * DFF + ksp*(DFF/KSPLIT) + jua*16;
    }
    const float* bRow[4];
    #pragma unroll
    for (int q = 0; q < 4; ++q) {
        int brow = ct*128 + q*32 + rqb;
        bRow[q] = w2 + ((size_t)e * K_DIM + brow) * DFF + ksp*(DFF/KSPLIT) + jub*8;
    }

    const int lane = t & 63, wv = t >> 6;
    const int wr = wv >> 1, wc = wv & 1;
    const int l15 = lane & 15, lq = lane >> 4;

    f32x4 acc[4][4];
    #pragma unroll
    for (int m = 0; m < 4; ++m)
        #pragma unroll
        for (int nn = 0; nn < 4; ++nn) acc[m][nn] = (f32x4){0.f,0.f,0.f,0.f};

    bf16x8 qa[4];
    f32x4  rb[8];

#define G2_LOAD(KT_) do { \
    _Pragma("unroll") for (int q = 0; q < 2; ++q) { \
        const bf16x8* ap_ = (const bf16x8*)(aRow[q] + (KT_)*64); \
        qa[2*q] = ap_[0]; qa[2*q+1] = ap_[1]; \
    } \
    _Pragma("unroll") for (int q = 0; q < 4; ++q) { \
        const f32x4* bp_ = (const f32x4*)(bRow[q] + (KT_)*64); \
        rb[2*q] = bp_[0]; rb[2*q+1] = bp_[1]; \
    } } while (0)

#define G2_STORE() do { \
    _Pragma("unroll") for (int q = 0; q < 2; ++q) { \
        int ra_ = q*64 + rqa; \
        Asv[ra_*8 + ((2*jua)   ^ (ra_ & 7))] = qa[2*q]; \
        Asv[ra_*8 + ((2*jua+1) ^ (ra_ & 7))] = qa[2*q+1]; \
    } \
    _Pragma("unroll") for (int q = 0; q < 4; ++q) { \
        int rb_ = q*32 + rqb; \
        f32x4 lo = rb[2*q], hi = rb[2*q+1]; bf16x8 v; \
        _Pragma("unroll") for (int j = 0; j < 4; ++j) { v[j]=(bf16)lo[j]; v[j+4]=(bf16)hi[j]; } \
        Bsv[rb_*8 + (jub ^ (rb_ & 7))] = v; \
    } } while (0)

#define G2_COMPUTE() do { \
    _Pragma("unroll") for (int ks = 0; ks < 2; ++ks) { \
        bf16x8 af[4], bf[4]; \
        _Pragma("unroll") for (int m = 0; m < 4; ++m) { \
            int fr = wr*64 + m*16 + l15; \
            af[m] = Asv[fr*8 + ((ks*4 + lq) ^ (fr & 7))]; \
        } \
        _Pragma("unroll") for (int nn = 0; nn < 4; ++nn) { \
            int fr = wc*64 + nn*16 + l15; \
            bf[nn] = Bsv[fr*8 + ((ks*4 + lq) ^ (fr & 7))]; \
        } \
        _Pragma("unroll") for (int m = 0; m < 4; ++m) \
            _Pragma("unroll") for (int nn = 0; nn < 4; ++nn) \
                acc[m][nn] = __builtin_amdgcn_mfma_f32_16x16x32_bf16(af[m], bf[nn], acc[m][nn], 0, 0, 0); \
    } } while (0)

    G2_LOAD(0);
    for (int kt = 0; kt < KT2; ++kt) {
        if (kt) __syncthreads();
        G2_STORE();
        if (kt + 1 < KT2) G2_LOAD(kt + 1);
        __syncthreads();
        G2_COMPUTE();
    }

    #pragma unroll
    for (int m = 0; m < 4; ++m)
        #pragma unroll
        for (int nn = 0; nn < 4; ++nn)
            #pragma unroll
            for (int r = 0; r < 4; ++r) {
                int rl = wr*64 + m*16 + lq*4 + r;
                int grow = r0 + rl;
                if (grow < n) {
                    int idx = base + grow;
                    int tok   = row_token[idx];
                    float wgt = row_wgt[idx];
                    int col = ct*128 + wc*64 + nn*16 + l15;
                    atomicAdd(out + (size_t)tok * K_DIM + col, wgt * acc[m][nn][r]);
                }
            }
#undef G2_LOAD
#undef G2_STORE
#undef G2_COMPUTE
}

// ---------------------------------------------------------------------------
extern "C" void kernel_launch(void* const* d_in, const int* in_sizes, int n_in,
                              void* d_out, int out_size, void* d_ws, size_t ws_size,
                              hipStream_t stream)
{
    const float* X   = (const float*)d_in[0];
    const float* w1  = (const float*)d_in[1];
    const float* w2  = (const float*)d_in[2];
    const float* tw  = (const float*)d_in[3];
    const int*   ids = (const int*)d_in[4];   // int64 in reference -> int32 from harness
    float* out = (float*)d_out;

    // ws layout: act (bf16 4096x2816) | row_token | row_wgt | counts | offs
    bf16* act      = (bf16*)d_ws;
    int*  row_token= (int*)((char*)d_ws + (size_t)NROWS * DFF * sizeof(bf16));
    float* row_wgt = (float*)(row_token + NROWS);
    int*  counts   = (int*)(row_wgt + NROWS);
    int*  offs     = counts + E_NUM;

    hipMemsetAsync(d_out, 0, (size_t)out_size * sizeof(float), stream);
    route_kernel<<<1, 512, 0, stream>>>(ids, tw, counts, offs, row_token, row_wgt);
    gemm1_kernel<<<dim3(DFF/64, NROWS/128, E_NUM), 256, 0, stream>>>(X, w1, counts, offs, row_token, act);
    gemm2_kernel<<<dim3((K_DIM/128)*KSPLIT, NROWS/128, E_NUM), 256, 0, stream>>>(act, w2, counts, offs, row_token, row_wgt, out);
}

// Round 7
// 276.870 us; speedup vs baseline: 3.0583x; 3.0583x over previous
//
#include <hip/hip_runtime.h>
#include <hip/hip_bf16.h>

#define M_TOK 2048
#define K_DIM 1024
#define E_NUM 8
#define DFF   2816
#define TOPK  2
#define NROWS (M_TOK*TOPK)   // 4096 routed rows

typedef __bf16 bf16;
typedef __bf16 bf16x8 __attribute__((ext_vector_type(8)));
typedef float  f32x4  __attribute__((ext_vector_type(4)));

// ---------------------------------------------------------------------------
// Routing (unchanged, verified): per-expert compacted token lists.
// ---------------------------------------------------------------------------
__global__ __launch_bounds__(512)
void route_kernel(const int* __restrict__ ids,
                  const float* __restrict__ tw,
                  int* __restrict__ counts, int* __restrict__ offs,
                  int* __restrict__ row_token, float* __restrict__ row_wgt)
{
    const int e    = threadIdx.x >> 6;
    const int lane = threadIdx.x & 63;
    __shared__ int scnt[E_NUM];

    int cnt = 0;
    for (int i0 = 0; i0 < NROWS; i0 += 64) {
        int id = ids[i0 + lane];
        cnt += __popcll(__ballot(id == e));
    }
    if (lane == 0) scnt[e] = cnt;
    __syncthreads();
    int base = 0;
    for (int j = 0; j < e; ++j) base += scnt[j];
    if (lane == 0) { counts[e] = cnt; offs[e] = base; }

    const unsigned long long ltmask = (1ull << lane) - 1ull;
    int pos = base;
    for (int i0 = 0; i0 < NROWS; i0 += 64) {
        int i = i0 + lane;
        int id = ids[i];
        unsigned long long m = __ballot(id == e);
        if (id == e) {
            int rank = __popcll(m & ltmask);
            row_token[pos + rank] = i >> 1;      // TOPK==2
            row_wgt[pos + rank]   = tw[i];
        }
        pos += __popcll(m);
    }
}

// ---------------------------------------------------------------------------
// GEMM1 + silu_and_mul. Tile 128 rows x 64 act-cols (B = 64 gate + 64 up rows).
// Single-buffered LDS (32 KiB) + 1-deep reg prefetch.
// launch_bounds(256,2): round-6 lesson — (256,4) caps unified VGPR+AGPR at
// 128 and spills the prefetch regs to scratch (1.15 GB writes, 4x slower).
// ---------------------------------------------------------------------------
__global__ __launch_bounds__(256, 2)
void gemm1_kernel(const float* __restrict__ X, const float* __restrict__ w1,
                  const int* __restrict__ counts, const int* __restrict__ offs,
                  const int* __restrict__ row_token, bf16* __restrict__ act)
{
    const int e  = blockIdx.z;
    const int rt = blockIdx.y;
    const int ct = blockIdx.x;              // 0..43
    const int n  = counts[e];
    const int r0 = rt * 128;
    if (r0 >= n) return;
    const int base = offs[e];

    __shared__ __align__(16) bf16 As[128*64];
    __shared__ __align__(16) bf16 Bs[128*64];
    bf16x8* Asv = (bf16x8*)As;
    bf16x8* Bsv = (bf16x8*)Bs;

    const int t   = threadIdx.x;
    const int rq0 = t >> 3;                 // 0..31
    const int ju  = t & 7;                  // 32B unit within 256B row-slice

    const float* aRow[4];
    const float* bRow[4];
    #pragma unroll
    for (int q = 0; q < 4; ++q) {
        int rl = r0 + q*32 + rq0; if (rl > n - 1) rl = n - 1;
        aRow[q] = X + (size_t)row_token[base + rl] * K_DIM + ju*8;
        int brow = q*32 + rq0;              // 0..127
        int w1row = (brow < 64) ? (ct*64 + brow) : (DFF + ct*64 + brow - 64);
        bRow[q] = w1 + ((size_t)e * (2*DFF) + w1row) * K_DIM + ju*8;
    }

    const int lane = t & 63, wv = t >> 6;
    const int wr = wv >> 1, wc = wv & 1;
    const int l15 = lane & 15, lq = lane >> 4;

    f32x4 accG[4][2], accU[4][2];
    #pragma unroll
    for (int m = 0; m < 4; ++m)
        #pragma unroll
        for (int nn = 0; nn < 2; ++nn) {
            accG[m][nn] = (f32x4){0.f,0.f,0.f,0.f};
            accU[m][nn] = (f32x4){0.f,0.f,0.f,0.f};
        }

    f32x4 ra[8], rb[8];

#define G1_LOAD(KT_) do { \
    _Pragma("unroll") for (int q = 0; q < 4; ++q) { \
        const f32x4* ap_ = (const f32x4*)(aRow[q] + (KT_)*64); \
        ra[2*q] = ap_[0]; ra[2*q+1] = ap_[1]; \
        const f32x4* bp_ = (const f32x4*)(bRow[q] + (KT_)*64); \
        rb[2*q] = bp_[0]; rb[2*q+1] = bp_[1]; \
    } } while (0)

#define G1_STORE() do { \
    _Pragma("unroll") for (int q = 0; q < 4; ++q) { \
        int rq_ = q*32 + rq0; \
        f32x4 lo = ra[2*q], hi = ra[2*q+1]; bf16x8 v; \
        _Pragma("unroll") for (int j = 0; j < 4; ++j) { v[j]=(bf16)lo[j]; v[j+4]=(bf16)hi[j]; } \
        Asv[rq_*8 + (ju ^ (rq_ & 7))] = v; \
        f32x4 lo2 = rb[2*q], hi2 = rb[2*q+1]; bf16x8 v2; \
        _Pragma("unroll") for (int j = 0; j < 4; ++j) { v2[j]=(bf16)lo2[j]; v2[j+4]=(bf16)hi2[j]; } \
        Bsv[rq_*8 + (ju ^ (rq_ & 7))] = v2; \
    } } while (0)

#define G1_COMPUTE() do { \
    _Pragma("unroll") for (int ks = 0; ks < 2; ++ks) { \
        bf16x8 af[4], bg[2], bu[2]; \
        _Pragma("unroll") for (int m = 0; m < 4; ++m) { \
            int fr = wr*64 + m*16 + l15; \
            af[m] = Asv[fr*8 + ((ks*4 + lq) ^ (fr & 7))]; \
        } \
        _Pragma("unroll") for (int nn = 0; nn < 2; ++nn) { \
            int frg = wc*32 + nn*16 + l15; \
            bg[nn] = Bsv[frg*8 + ((ks*4 + lq) ^ (frg & 7))]; \
            int fru = 64 + wc*32 + nn*16 + l15; \
            bu[nn] = Bsv[fru*8 + ((ks*4 + lq) ^ (fru & 7))]; \
        } \
        _Pragma("unroll") for (int m = 0; m < 4; ++m) \
            _Pragma("unroll") for (int nn = 0; nn < 2; ++nn) { \
                accG[m][nn] = __builtin_amdgcn_mfma_f32_16x16x32_bf16(af[m], bg[nn], accG[m][nn], 0, 0, 0); \
                accU[m][nn] = __builtin_amdgcn_mfma_f32_16x16x32_bf16(af[m], bu[nn], accU[m][nn], 0, 0, 0); \
            } \
    } } while (0)

    const int KT = K_DIM / 64;   // 16
    G1_LOAD(0);
    for (int kt = 0; kt < KT; ++kt) {
        if (kt) __syncthreads();            // prev compute done reading buf
        G1_STORE();                          // waits on LOAD(kt)
        if (kt + 1 < KT) G1_LOAD(kt + 1);   // in flight across compute
        __syncthreads();
        G1_COMPUTE();
    }

    // epilogue: act = silu(gate) * up  (C/D: col=lane&15, row=(lane>>4)*4+r)
    #pragma unroll
    for (int m = 0; m < 4; ++m)
        #pragma unroll
        for (int nn = 0; nn < 2; ++nn)
            #pragma unroll
            for (int r = 0; r < 4; ++r) {
                int rl = wr*64 + m*16 + lq*4 + r;
                int grow = r0 + rl;
                if (grow < n) {
                    float g = accG[m][nn][r];
                    float u = accU[m][nn][r];
                    float a = (g / (1.f + __expf(-g))) * u;
                    int col = ct*64 + wc*32 + nn*16 + l15;
                    act[(size_t)(base + grow) * DFF + col] = (bf16)a;
                }
            }
#undef G1_LOAD
#undef G1_STORE
#undef G1_COMPUTE
}

// ---------------------------------------------------------------------------
// GEMM2: y = act @ w2[e]^T, atomic scatter epilogue. Tile 128 x 128.
// Single-buffered LDS + KSPLIT=2 + 1-deep reg prefetch. launch_bounds(256,2).
// ---------------------------------------------------------------------------
#define KSPLIT 2
#define KT2    (DFF / 64 / KSPLIT)   // 22

__global__ __launch_bounds__(256, 2)
void gemm2_kernel(const bf16* __restrict__ act, const float* __restrict__ w2,
                  const int* __restrict__ counts, const int* __restrict__ offs,
                  const int* __restrict__ row_token, const float* __restrict__ row_wgt,
                  float* __restrict__ out)
{
    const int e   = blockIdx.z;
    const int rt  = blockIdx.y;
    const int ct  = blockIdx.x >> 1;          // 0..7 : 128 out cols
    const int ksp = blockIdx.x & 1;           // DFF half
    const int n   = counts[e];
    const int r0  = rt * 128;
    if (r0 >= n) return;
    const int base = offs[e];

    __shared__ __align__(16) bf16 As[128*64];
    __shared__ __align__(16) bf16 Bs[128*64];
    bf16x8* Asv = (bf16x8*)As;
    bf16x8* Bsv = (bf16x8*)Bs;

    const int t = threadIdx.x;
    const int rqa = t >> 2, jua = t & 3;      // A: 4 units(32B) per 128B row
    const int rqb = t >> 3, jub = t & 7;      // B: 8 units(32B) per 256B row

    const bf16* aRow[2];
    #pragma unroll
    for (int q = 0; q < 2; ++q) {
        int rl = r0 + q*64 + rqa; if (rl > n - 1) rl = n - 1;
        aRow[q] = act + (size_t)(base + rl) * DFF + ksp*(DFF/KSPLIT) + jua*16;
    }
    const float* bRow[4];
    #pragma unroll
    for (int q = 0; q < 4; ++q) {
        int brow = ct*128 + q*32 + rqb;
        bRow[q] = w2 + ((size_t)e * K_DIM + brow) * DFF + ksp*(DFF/KSPLIT) + jub*8;
    }

    const int lane = t & 63, wv = t >> 6;
    const int wr = wv >> 1, wc = wv & 1;
    const int l15 = lane & 15, lq = lane >> 4;

    f32x4 acc[4][4];
    #pragma unroll
    for (int m = 0; m < 4; ++m)
        #pragma unroll
        for (int nn = 0; nn < 4; ++nn) acc[m][nn] = (f32x4){0.f,0.f,0.f,0.f};

    bf16x8 qa[4];
    f32x4  rb[8];

#define G2_LOAD(KT_) do { \
    _Pragma("unroll") for (int q = 0; q < 2; ++q) { \
        const bf16x8* ap_ = (const bf16x8*)(aRow[q] + (KT_)*64); \
        qa[2*q] = ap_[0]; qa[2*q+1] = ap_[1]; \
    } \
    _Pragma("unroll") for (int q = 0; q < 4; ++q) { \
        const f32x4* bp_ = (const f32x4*)(bRow[q] + (KT_)*64); \
        rb[2*q] = bp_[0]; rb[2*q+1] = bp_[1]; \
    } } while (0)

#define G2_STORE() do { \
    _Pragma("unroll") for (int q = 0; q < 2; ++q) { \
        int ra_ = q*64 + rqa; \
        Asv[ra_*8 + ((2*jua)   ^ (ra_ & 7))] = qa[2*q]; \
        Asv[ra_*8 + ((2*jua+1) ^ (ra_ & 7))] = qa[2*q+1]; \
    } \
    _Pragma("unroll") for (int q = 0; q < 4; ++q) { \
        int rb_ = q*32 + rqb; \
        f32x4 lo = rb[2*q], hi = rb[2*q+1]; bf16x8 v; \
        _Pragma("unroll") for (int j = 0; j < 4; ++j) { v[j]=(bf16)lo[j]; v[j+4]=(bf16)hi[j]; } \
        Bsv[rb_*8 + (jub ^ (rb_ & 7))] = v; \
    } } while (0)

#define G2_COMPUTE() do { \
    _Pragma("unroll") for (int ks = 0; ks < 2; ++ks) { \
        bf16x8 af[4], bf[4]; \
        _Pragma("unroll") for (int m = 0; m < 4; ++m) { \
            int fr = wr*64 + m*16 + l15; \
            af[m] = Asv[fr*8 + ((ks*4 + lq) ^ (fr & 7))]; \
        } \
        _Pragma("unroll") for (int nn = 0; nn < 4; ++nn) { \
            int fr = wc*64 + nn*16 + l15; \
            bf[nn] = Bsv[fr*8 + ((ks*4 + lq) ^ (fr & 7))]; \
        } \
        _Pragma("unroll") for (int m = 0; m < 4; ++m) \
            _Pragma("unroll") for (int nn = 0; nn < 4; ++nn) \
                acc[m][nn] = __builtin_amdgcn_mfma_f32_16x16x32_bf16(af[m], bf[nn], acc[m][nn], 0, 0, 0); \
    } } while (0)

    G2_LOAD(0);
    for (int kt = 0; kt < KT2; ++kt) {
        if (kt) __syncthreads();
        G2_STORE();
        if (kt + 1 < KT2) G2_LOAD(kt + 1);
        __syncthreads();
        G2_COMPUTE();
    }

    #pragma unroll
    for (int m = 0; m < 4; ++m)
        #pragma unroll
        for (int nn = 0; nn < 4; ++nn)
            #pragma unroll
            for (int r = 0; r < 4; ++r) {
                int rl = wr*64 + m*16 + lq*4 + r;
                int grow = r0 + rl;
                if (grow < n) {
                    int idx = base + grow;
                    int tok   = row_token[idx];
                    float wgt = row_wgt[idx];
                    int col = ct*128 + wc*64 + nn*16 + l15;
                    atomicAdd(out + (size_t)tok * K_DIM + col, wgt * acc[m][nn][r]);
                }
            }
#undef G2_LOAD
#undef G2_STORE
#undef G2_COMPUTE
}

// ---------------------------------------------------------------------------
extern "C" void kernel_launch(void* const* d_in, const int* in_sizes, int n_in,
                              void* d_out, int out_size, void* d_ws, size_t ws_size,
                              hipStream_t stream)
{
    const float* X   = (const float*)d_in[0];
    const float* w1  = (const float*)d_in[1];
    const float* w2  = (const float*)d_in[2];
    const float* tw  = (const float*)d_in[3];
    const int*   ids = (const int*)d_in[4];   // int64 in reference -> int32 from harness
    float* out = (float*)d_out;

    // ws layout: act (bf16 4096x2816) | row_token | row_wgt | counts | offs
    bf16* act      = (bf16*)d_ws;
    int*  row_token= (int*)((char*)d_ws + (size_t)NROWS * DFF * sizeof(bf16));
    float* row_wgt = (float*)(row_token + NROWS);
    int*  counts   = (int*)(row_wgt + NROWS);
    int*  offs     = counts + E_NUM;

    hipMemsetAsync(d_out, 0, (size_t)out_size * sizeof(float), stream);
    route_kernel<<<1, 512, 0, stream>>>(ids, tw, counts, offs, row_token, row_wgt);
    gemm1_kernel<<<dim3(DFF/64, NROWS/128, E_NUM), 256, 0, stream>>>(X, w1, counts, offs, row_token, act);
    gemm2_kernel<<<dim3((K_DIM/128)*KSPLIT, NROWS/128, E_NUM), 256, 0, stream>>>(act, w2, counts, offs, row_token, row_wgt, out);
}